// Round 2
// baseline (276.067 us; speedup 1.0000x reference)
//
#include <hip/hip_runtime.h>

#define B_DIM 512
#define T_DIM 4096
#define NSLOT 256
#define THREADS 256
#define ITER 8
#define QROWS (B_DIM * T_DIM * 4)           // 8,388,608 quarter-rows (4 lanes per 16-elem row)
#define BLOCKS (QROWS / (THREADS * ITER))   // 4096 blocks, each covers 512 contiguous rows => one batch b

__device__ __forceinline__ float hsum4(float4 v) { return (v.x + v.y) + (v.z + v.w); }

__device__ __forceinline__ float mdot(float4 x, float4 m) {
    return (x.x * m.x + x.y * m.y) + (x.z * m.z + x.w * m.w);
}

__device__ __forceinline__ float mdot2(float4 x, float4 m) {
    return (x.x * x.x * m.x + x.y * x.y * m.y) + (x.z * x.z * m.z + x.w * x.w * m.w);
}

// Sum across an aligned 4-lane quad via DPP quad_perm (pure VALU).
__device__ __forceinline__ float qsum(float v) {
    int t = __builtin_amdgcn_update_dpp(0, __float_as_int(v), 0xB1, 0xF, 0xF, true); // xor1
    v += __int_as_float(t);
    t = __builtin_amdgcn_update_dpp(0, __float_as_int(v), 0x4E, 0xF, 0xF, true);     // xor2
    v += __int_as_float(t);
    return v;
}

// Streaming kernel, 4 lanes per (b,t) row. Load phase FIRST: all 16 float4
// loads issued as one cluster into register arrays (static indices only),
// THEN the compute phase. Forces deep vmcnt pipelining — round-1's version
// let the scheduler sink loads to their uses (VGPR_Count=24 => ~2 loads in
// flight => latency-bound at 16% BW). launch_bounds(,2) allows up to 256
// VGPRs so the payload (64 VGPRs) + pipeline headroom fits.
__global__ __launch_bounds__(THREADS, 2) void rcl_main(
    const float4* __restrict__ pred4, const float4* __restrict__ targ4,
    const float4* __restrict__ mask4, double* __restrict__ slots)
{
    const int tid  = threadIdx.x;
    const int b    = blockIdx.x >> 3;                  // 8 blocks per batch (T=4096 rows)
    const int base = blockIdx.x * (THREADS * ITER);    // first quarter-row of this block

    // Mask: one 16-B load per thread, quad position = tid&3 (L2-hot 32 KB array).
    const float4 mv = mask4[(b << 2) + (tid & 3)];
    const float n = qsum(hsum4(mv));                   // n, uniform across block
    if (n <= 1.0f) return;                             // slots are pre-zeroed

    // ---- load phase: 16 independent global_load_dwordx4, all in flight ----
    float4 p[ITER], q[ITER];
#pragma unroll
    for (int i = 0; i < ITER; i++) {
        const int g = base + i * THREADS + tid;        // contiguous, fully coalesced
        p[i] = pred4[g];
        q[i] = targ4[g];
    }

    // ---- compute phase ----
    const float inv = 1.0f / (n * (n - 1.0f));
    float csum = 0.0f;
#pragma unroll
    for (int i = 0; i < ITER; i++) {
        float sp  = qsum(mdot(p[i], mv));
        float sp2 = qsum(mdot2(p[i], mv));
        float sq  = qsum(mdot(q[i], mv));
        float sq2 = qsum(mdot2(q[i], mv));
        // unbiased var = (n*s2 - s*s) / (n*(n-1))
        float d = ((n * sp2 - sp * sp) - (n * sq2 - sq * sq)) * inv;
        csum += d * d * 0.25f;                         // 4 lanes hold identical d^2
    }

    for (int off = 32; off > 0; off >>= 1)
        csum += __shfl_down(csum, off, 64);

    __shared__ float partial[THREADS / 64];
    const int w = tid >> 6;
    const int lane = tid & 63;
    if (lane == 0) partial[w] = csum;
    __syncthreads();
    if (tid == 0) {
        float s = (partial[0] + partial[1]) + (partial[2] + partial[3]);
        atomicAdd(&slots[blockIdx.x & (NSLOT - 1)], (double)s);
    }
}

// Reduce 256 slots + recompute n_multi from the (cached) mask.
__global__ __launch_bounds__(256) void rcl_final(
    const double* __restrict__ slots, const float4* __restrict__ mask4,
    float* __restrict__ out)
{
    __shared__ double dred[256];
    __shared__ float fred[256];
    const int t = threadIdx.x;

    double tot = slots[t];

    float cnt = 0.0f;
    for (int bb = t; bb < B_DIM; bb += 256) {
        const float4* mp = mask4 + (bb << 2);
        float nn = (hsum4(mp[0]) + hsum4(mp[1])) + (hsum4(mp[2]) + hsum4(mp[3]));
        cnt += (nn > 1.0f) ? 1.0f : 0.0f;
    }

    dred[t] = tot;
    fred[t] = cnt;
    __syncthreads();
    for (int s = 128; s > 0; s >>= 1) {
        if (t < s) { dred[t] += dred[t + s]; fred[t] += fred[t + s]; }
        __syncthreads();
    }
    if (t == 0) {
        double nm = (double)fred[0];
        out[0] = (nm > 0.0) ? (float)(0.1 * (dred[0] / ((double)T_DIM * nm))) : 0.0f;
    }
}

extern "C" void kernel_launch(void* const* d_in, const int* in_sizes, int n_in,
                              void* d_out, int out_size, void* d_ws, size_t ws_size,
                              hipStream_t stream) {
    const float4* pred4 = (const float4*)d_in[0];
    const float4* targ4 = (const float4*)d_in[1];
    const float4* mask4 = (const float4*)d_in[2];
    float* out = (float*)d_out;

    double* slots = (double*)d_ws;  // NSLOT doubles

    hipMemsetAsync(d_ws, 0, NSLOT * sizeof(double), stream);
    rcl_main<<<BLOCKS, THREADS, 0, stream>>>(pred4, targ4, mask4, slots);
    rcl_final<<<1, 256, 0, stream>>>(slots, mask4, out);
}

// Round 3
// 273.885 us; speedup vs baseline: 1.0080x; 1.0080x over previous
//
#include <hip/hip_runtime.h>

#define B_DIM 512
#define T_DIM 4096
#define NSLOT 256
#define THREADS 256
#define ITER 8
#define QROWS (B_DIM * T_DIM * 4)           // 8,388,608 quarter-rows (4 lanes per 16-elem row)
#define BLOCKS (QROWS / (THREADS * ITER))   // 4096 blocks, each covers 512 contiguous rows => one batch b

__device__ __forceinline__ float hsum4(float4 v) { return (v.x + v.y) + (v.z + v.w); }

__device__ __forceinline__ float mdot(float4 x, float4 m) {
    return (x.x * m.x + x.y * m.y) + (x.z * m.z + x.w * m.w);
}

__device__ __forceinline__ float mdot2(float4 x, float4 m) {
    return (x.x * x.x * m.x + x.y * x.y * m.y) + (x.z * x.z * m.z + x.w * x.w * m.w);
}

// Sum across an aligned 4-lane quad via DPP quad_perm (pure VALU).
__device__ __forceinline__ float qsum(float v) {
    int t = __builtin_amdgcn_update_dpp(0, __float_as_int(v), 0xB1, 0xF, 0xF, true); // xor1
    v += __int_as_float(t);
    t = __builtin_amdgcn_update_dpp(0, __float_as_int(v), 0x4E, 0xF, 0xF, true);     // xor2
    v += __int_as_float(t);
    return v;
}

// Streaming kernel, 4 lanes per (b,t) row. The load cluster is pinned AHEAD
// of all compute with sched_barrier(0): rounds 1-2 proved the machine
// scheduler sinks loads to their uses (VGPR=24/36 => ~2 loads in flight =>
// latency-bound at 16% HBM). With the fence, all 16 global_load_dwordx4
// issue back-to-back (16 KB/wave in flight) and the waitcnt pass emits
// counted vmcnt(N) per use. Diagnostic: VGPR_Count must jump to ~100.
__global__ __launch_bounds__(THREADS, 2) void rcl_main(
    const float4* __restrict__ pred4, const float4* __restrict__ targ4,
    const float4* __restrict__ mask4, double* __restrict__ slots)
{
    const int tid  = threadIdx.x;
    const int b    = blockIdx.x >> 3;                  // 8 blocks per batch (T=4096 rows)
    const int base = blockIdx.x * (THREADS * ITER);    // first quarter-row of this block

    // Mask: one 16-B load per thread, quad position = tid&3 (L2-hot 32 KB array).
    const float4 mv = mask4[(b << 2) + (tid & 3)];
    const float n = qsum(hsum4(mv));                   // n, uniform across block
    if (n <= 1.0f) return;                             // slots are pre-zeroed

    // ---- load phase: 16 independent global_load_dwordx4, all in flight ----
    float4 p[ITER], q[ITER];
#pragma unroll
    for (int i = 0; i < ITER; i++) {
        const int g = base + i * THREADS + tid;        // contiguous, fully coalesced
        p[i] = pred4[g];
        q[i] = targ4[g];
    }
    // Hard scheduling fence: nothing crosses. Loads stay clustered above.
    __builtin_amdgcn_sched_barrier(0);

    // ---- compute phase ----
    const float inv = 1.0f / (n * (n - 1.0f));
    float csum = 0.0f;
#pragma unroll
    for (int i = 0; i < ITER; i++) {
        float sp  = qsum(mdot(p[i], mv));
        float sp2 = qsum(mdot2(p[i], mv));
        float sq  = qsum(mdot(q[i], mv));
        float sq2 = qsum(mdot2(q[i], mv));
        // unbiased var = (n*s2 - s*s) / (n*(n-1))
        float d = ((n * sp2 - sp * sp) - (n * sq2 - sq * sq)) * inv;
        csum += d * d * 0.25f;                         // 4 lanes hold identical d^2
    }

    for (int off = 32; off > 0; off >>= 1)
        csum += __shfl_down(csum, off, 64);

    __shared__ float partial[THREADS / 64];
    const int w = tid >> 6;
    const int lane = tid & 63;
    if (lane == 0) partial[w] = csum;
    __syncthreads();
    if (tid == 0) {
        float s = (partial[0] + partial[1]) + (partial[2] + partial[3]);
        atomicAdd(&slots[blockIdx.x & (NSLOT - 1)], (double)s);
    }
}

// Reduce 256 slots + recompute n_multi from the (cached) mask.
__global__ __launch_bounds__(256) void rcl_final(
    const double* __restrict__ slots, const float4* __restrict__ mask4,
    float* __restrict__ out)
{
    __shared__ double dred[256];
    __shared__ float fred[256];
    const int t = threadIdx.x;

    double tot = slots[t];

    float cnt = 0.0f;
    for (int bb = t; bb < B_DIM; bb += 256) {
        const float4* mp = mask4 + (bb << 2);
        float nn = (hsum4(mp[0]) + hsum4(mp[1])) + (hsum4(mp[2]) + hsum4(mp[3]));
        cnt += (nn > 1.0f) ? 1.0f : 0.0f;
    }

    dred[t] = tot;
    fred[t] = cnt;
    __syncthreads();
    for (int s = 128; s > 0; s >>= 1) {
        if (t < s) { dred[t] += dred[t + s]; fred[t] += fred[t + s]; }
        __syncthreads();
    }
    if (t == 0) {
        double nm = (double)fred[0];
        out[0] = (nm > 0.0) ? (float)(0.1 * (dred[0] / ((double)T_DIM * nm))) : 0.0f;
    }
}

extern "C" void kernel_launch(void* const* d_in, const int* in_sizes, int n_in,
                              void* d_out, int out_size, void* d_ws, size_t ws_size,
                              hipStream_t stream) {
    const float4* pred4 = (const float4*)d_in[0];
    const float4* targ4 = (const float4*)d_in[1];
    const float4* mask4 = (const float4*)d_in[2];
    float* out = (float*)d_out;

    double* slots = (double*)d_ws;  // NSLOT doubles

    hipMemsetAsync(d_ws, 0, NSLOT * sizeof(double), stream);
    rcl_main<<<BLOCKS, THREADS, 0, stream>>>(pred4, targ4, mask4, slots);
    rcl_final<<<1, 256, 0, stream>>>(slots, mask4, out);
}